// Round 5
// baseline (356.609 us; speedup 1.0000x reference)
//
#include <hip/hip_runtime.h>

typedef unsigned short u16;
typedef unsigned int u32;
typedef __attribute__((ext_vector_type(8))) short short8;
typedef __attribute__((ext_vector_type(4))) float f32x4;

#define D_MODEL 1024
#define SEQ 2048
#define NH 16
#define DK 64
#define DFF 4096
#define NTOK 4096
#define LOG2E 1.44269504f

__device__ __forceinline__ u16 f2bf(float f) {
    unsigned x = __builtin_bit_cast(unsigned, f);
    x = x + 0x7fffu + ((x >> 16) & 1u);
    return (u16)(x >> 16);
}

__device__ __forceinline__ void gload_lds16(const void* g, void* l) {
    __builtin_amdgcn_global_load_lds(
        (__attribute__((address_space(1))) void*)g,
        (__attribute__((address_space(3))) void*)l, 16, 0, 0);
}

// ---------------- fp32 -> bf16 converts ----------------
__device__ __forceinline__ void cvt_body(const float* __restrict__ in,
                                         u16* __restrict__ out, int blk) {
    size_t i = ((size_t)blk * 256 + threadIdx.x) * 4;
    float4 v = *(const float4*)(in + i);
    out[i + 0] = f2bf(v.x);
    out[i + 1] = f2bf(v.y);
    out[i + 2] = f2bf(v.z);
    out[i + 3] = f2bf(v.w);
}

__global__ __launch_bounds__(256) void cvt_bf16(const float* __restrict__ in,
                                                u16* __restrict__ out) {
    cvt_body(in, out, blockIdx.x);
}

__global__ __launch_bounds__(256) void cvt_bf16_4(
    const float* __restrict__ s0, const float* __restrict__ s1,
    const float* __restrict__ s2, const float* __restrict__ s3,
    u16* __restrict__ d0, u16* __restrict__ d1, u16* __restrict__ d2,
    u16* __restrict__ d3) {
    int which = blockIdx.x >> 10, blk = blockIdx.x & 1023;
    const float* s = which == 0 ? s0 : which == 1 ? s1 : which == 2 ? s2 : s3;
    u16* d = which == 0 ? d0 : which == 1 ? d1 : which == 2 ? d2 : d3;
    cvt_body(s, d, blk);
}

__global__ __launch_bounds__(256) void cvt_bf16_2(
    const float* __restrict__ s0, const float* __restrict__ s1,
    u16* __restrict__ d0, u16* __restrict__ d1) {
    int which = blockIdx.x >> 12, blk = blockIdx.x & 4095;
    cvt_body(which ? s1 : s0, which ? d1 : d0, blk);
}

// ---------------- V transpose: [b,h,s,d] -> [b,h,d,s], pre-swizzled ----------------
__global__ __launch_bounds__(256) void transpose_v(const u16* __restrict__ V,
                                                   u16* __restrict__ Vt) {
    __shared__ u16 T[128 * 65];
    const int tid = threadIdx.x;
    const int bh = blockIdx.y;
    const int s0 = blockIdx.x * 128;
    const size_t base = (size_t)bh * SEQ * DK;
#pragma unroll
    for (int j = 0; j < 4; ++j) {
        int c = j * 256 + tid;
        int s = c >> 3, dc = c & 7;
        short8 v = *(const short8*)(V + base + (size_t)(s0 + s) * DK + dc * 8);
#pragma unroll
        for (int e = 0; e < 8; ++e) T[s * 65 + dc * 8 + e] = (u16)v[e];
    }
    __syncthreads();
    const size_t obase = (size_t)bh * DK * SEQ;
#pragma unroll
    for (int j = 0; j < 4; ++j) {
        int c = j * 256 + tid;
        int d = c >> 4, tc = c & 15;
        short8 v;
#pragma unroll
        for (int e = 0; e < 8; ++e) v[e] = (short)T[(tc * 8 + e) * 65 + d];
        *(short8*)(Vt + obase + (size_t)d * SEQ + s0 + ((tc ^ (d & 7)) * 8)) = v;
    }
}

// ---------------- GEMM core: BK=64, 128x128 tile ----------------
template <int BM, int BN>
__device__ __forceinline__ void gemm_acc64(const u16* __restrict__ A,
                                           const u16* __restrict__ W,
                                           int K, int m0, int n0,
                                           f32x4 (&acc)[BM / 32][BN / 32]) {
    constexpr int MR = BM / 32, NR = BN / 32;
    __shared__ short8 As[BM][8];
    __shared__ short8 Bs[BN][8];
    const int tid = threadIdx.x;
    const int lane = tid & 63, w = tid >> 6;
    const int l15 = lane & 15, lg = lane >> 4;
    const int wr = (w >> 1) * (BM / 2), wc = (w & 1) * (BN / 2);

#pragma unroll
    for (int i = 0; i < MR; ++i)
#pragma unroll
        for (int j = 0; j < NR; ++j) acc[i][j] = (f32x4){0.f, 0.f, 0.f, 0.f};

    for (int k0 = 0; k0 < K; k0 += 64) {
        __syncthreads();
#pragma unroll
        for (int j = 0; j < BM / 32; ++j) {
            int idx = j * 256 + tid;
            gload_lds16(A + (size_t)(m0 + (idx >> 3)) * K + k0 + (idx & 7) * 8,
                        (char*)As + (j * 256 + w * 64) * 16);
        }
#pragma unroll
        for (int j = 0; j < BN / 32; ++j) {
            int idx = j * 256 + tid;
            gload_lds16(W + (size_t)(n0 + (idx >> 3)) * K + k0 + (idx & 7) * 8,
                        (char*)Bs + (j * 256 + w * 64) * 16);
        }
        __syncthreads();

#pragma unroll
        for (int kk = 0; kk < 2; ++kk) {
            short8 af[MR], bf[NR];
#pragma unroll
            for (int m = 0; m < MR; ++m) af[m] = As[wr + m * 16 + l15][kk * 4 + lg];
#pragma unroll
            for (int n = 0; n < NR; ++n) bf[n] = Bs[wc + n * 16 + l15][kk * 4 + lg];
#pragma unroll
            for (int m = 0; m < MR; ++m)
#pragma unroll
                for (int n = 0; n < NR; ++n)
                    acc[m][n] = __builtin_amdgcn_mfma_f32_16x16x32_bf16(
                        af[m], bf[n], acc[m][n], 0, 0, 0);
        }
    }
}

// EPI 0: fp32 out row-major; EPI 1: relu bf16 row-major
template <int EPI>
__global__ __launch_bounds__(256) void gemm_bt64(
    const u16* __restrict__ A, const u16* __restrict__ W,
    const float* __restrict__ bias, u16* __restrict__ outb,
    float* __restrict__ outf, int M, int N, int K) {
    f32x4 acc[4][4];
    const int m0 = blockIdx.y * 128, n0 = blockIdx.x * 128;
    gemm_acc64<128, 128>(A, W, K, m0, n0, acc);
    const int lane = threadIdx.x & 63, w = threadIdx.x >> 6;
    const int l15 = lane & 15, lg = lane >> 4;
    const int wr = (w >> 1) * 64, wc = (w & 1) * 64;
#pragma unroll
    for (int m = 0; m < 4; ++m)
#pragma unroll
        for (int n = 0; n < 4; ++n) {
            int gn = n0 + wc + n * 16 + l15;
            float bv = bias[gn];
#pragma unroll
            for (int r = 0; r < 4; ++r) {
                int gm = m0 + wr + m * 16 + lg * 4 + r;
                float v = acc[m][n][r] + bv;
                if (EPI == 0) outf[(size_t)gm * N + gn] = v;
                else outb[(size_t)gm * N + gn] = f2bf(fmaxf(v, 0.f));
            }
        }
}

// fused QKV: blockIdx.x selects matrix; out in [B,H,S,dk], Q pre-scaled
__global__ __launch_bounds__(256) void gemm_qkv(
    const u16* __restrict__ A, const u16* __restrict__ Wq,
    const u16* __restrict__ Wk, const u16* __restrict__ Wv,
    const float* __restrict__ bq, const float* __restrict__ bk,
    const float* __restrict__ bv, u16* __restrict__ Qo, u16* __restrict__ Ko,
    u16* __restrict__ Vo) {
    const int mat = blockIdx.x >> 3;
    const u16* W = mat == 0 ? Wq : (mat == 1 ? Wk : Wv);
    const float* bias = mat == 0 ? bq : (mat == 1 ? bk : bv);
    u16* out = mat == 0 ? Qo : (mat == 1 ? Ko : Vo);
    const float scale = (mat == 0) ? 0.125f * LOG2E : 1.0f;
    f32x4 acc[4][4];
    const int m0 = blockIdx.y * 128, n0 = (blockIdx.x & 7) * 128;
    gemm_acc64<128, 128>(A, W, D_MODEL, m0, n0, acc);
    const int lane = threadIdx.x & 63, w = threadIdx.x >> 6;
    const int l15 = lane & 15, lg = lane >> 4;
    const int wr = (w >> 1) * 64, wc = (w & 1) * 64;
#pragma unroll
    for (int m = 0; m < 4; ++m)
#pragma unroll
        for (int n = 0; n < 4; ++n) {
            int gn = n0 + wc + n * 16 + l15;
            float bv = bias[gn];
            int h = gn >> 6, d = gn & 63;
#pragma unroll
            for (int r = 0; r < 4; ++r) {
                int gm = m0 + wr + m * 16 + lg * 4 + r;
                int b = gm >> 11, s = gm & 2047;
                float v = (acc[m][n][r] + bv) * scale;
                out[(((size_t)(b * NH + h)) * SEQ + s) * DK + d] = f2bf(v);
            }
        }
}

// ---------------- 64x128 tile, BK=64 GEMM (fp32 out), optional split-K via blockIdx.z ----------------
__global__ __launch_bounds__(256) void gemm_k64(
    const u16* __restrict__ A, const u16* __restrict__ W,
    const float* __restrict__ bias, float* __restrict__ outf,
    float* __restrict__ outf2, int M, int N, int K) {
    __shared__ short8 As[64][8];
    __shared__ short8 Bs[128][8];
    const int tid = threadIdx.x;
    const int lane = tid & 63, w = tid >> 6;
    const int l15 = lane & 15, lg = lane >> 4;
    const int wr = (w >> 1) * 32, wc = (w & 1) * 64;
    const int m0 = blockIdx.y * 64, n0 = blockIdx.x * 128;
    const int kz = blockIdx.z;
    const int kl = K / gridDim.z, kbase = kz * kl;
    float* out = kz ? outf2 : outf;

    f32x4 acc[2][4];
#pragma unroll
    for (int i = 0; i < 2; ++i)
#pragma unroll
        for (int j = 0; j < 4; ++j) acc[i][j] = (f32x4){0.f, 0.f, 0.f, 0.f};

    for (int k0 = kbase; k0 < kbase + kl; k0 += 64) {
        __syncthreads();
#pragma unroll
        for (int j = 0; j < 2; ++j) {
            int idx = j * 256 + tid;
            gload_lds16(A + (size_t)(m0 + (idx >> 3)) * K + k0 + (idx & 7) * 8,
                        (char*)As + (j * 256 + w * 64) * 16);
        }
#pragma unroll
        for (int j = 0; j < 4; ++j) {
            int idx = j * 256 + tid;
            gload_lds16(W + (size_t)(n0 + (idx >> 3)) * K + k0 + (idx & 7) * 8,
                        (char*)Bs + (j * 256 + w * 64) * 16);
        }
        __syncthreads();

#pragma unroll
        for (int kk = 0; kk < 2; ++kk) {
            short8 af[2], bf[4];
#pragma unroll
            for (int m = 0; m < 2; ++m) af[m] = As[wr + m * 16 + l15][kk * 4 + lg];
#pragma unroll
            for (int n = 0; n < 4; ++n) bf[n] = Bs[wc + n * 16 + l15][kk * 4 + lg];
#pragma unroll
            for (int m = 0; m < 2; ++m)
#pragma unroll
                for (int n = 0; n < 4; ++n)
                    acc[m][n] = __builtin_amdgcn_mfma_f32_16x16x32_bf16(
                        af[m], bf[n], acc[m][n], 0, 0, 0);
        }
    }

#pragma unroll
    for (int m = 0; m < 2; ++m)
#pragma unroll
        for (int n = 0; n < 4; ++n) {
            int gn = n0 + wc + n * 16 + l15;
            float bv = (kz == 0) ? bias[gn] : 0.f;
#pragma unroll
            for (int r = 0; r < 4; ++r) {
                int gm = m0 + wr + m * 16 + lg * 4 + r;
                out[(size_t)gm * N + gn] = acc[m][n][r] + bv;
            }
        }
}

// ---------------- flash attention: swapped QK^T, lane-local softmax, ones-MFMA row sums ----------------
#define KVB 64
__global__ __launch_bounds__(256) void attn_fwd(const u16* __restrict__ Q,
                                                const u16* __restrict__ Kp,
                                                const u16* __restrict__ Vg_,
                                                u16* __restrict__ ctx) {
    __shared__ __align__(16) u16 Vt[2][64 * 64];    // swizzled [d][t], 8KB each
    __shared__ __align__(16) u16 Ps[4][16 * 64];    // per-wave [q][kv], chunk^q&7 swizzle

    const int tid = threadIdx.x;
    const int lane = tid & 63;
    const int w = tid >> 6;
    const int l15 = lane & 15;
    const int lg = lane >> 4;
    const int bh = blockIdx.y;
    const int qbase = blockIdx.x * 64 + w * 16;
    const u16* Qb = Q + (size_t)bh * SEQ * DK;
    const u16* Kb = Kp + (size_t)bh * SEQ * DK;
    const u16* Vg = Vg_ + (size_t)bh * DK * SEQ;    // [d][s] pre-swizzled

    short8 qf[2];
#pragma unroll
    for (int hf = 0; hf < 2; ++hf)
        qf[hf] = *(const short8*)(Qb + (size_t)(qbase + l15) * DK + hf * 32 + lg * 8);

    short8 onesf;
#pragma unroll
    for (int e = 0; e < 8; ++e) onesf[e] = (short)0x3F80;  // bf16 1.0

    f32x4 zero = {0.f, 0.f, 0.f, 0.f};
    f32x4 o[4], o1 = zero;
#pragma unroll
    for (int db = 0; db < 4; ++db) o[db] = zero;
    float m_own = -1e30f;                            // running max for q = l15

    u16* Pu = Ps[w];
    const int psw = l15 & 7;

#define STAGE_V(T0, BUF)                                                       \
    {                                                                          \
        _Pragma("unroll") for (int j = 0; j < 2; ++j) {                        \
            int idx = j * 256 + tid;                                           \
            gload_lds16(Vg + (size_t)(idx >> 3) * SEQ + (T0) + (idx & 7) * 8,  \
                        (char*)Vt[BUF] + (j * 256 + w * 64) * 16);             \
        }                                                                      \
    }
#define LDK(T0, NB, HALF)                                                      \
    (*(const short8*)(Kb + (size_t)((T0) + (NB) * 16 + l15) * DK +             \
                      (HALF) * 32 + lg * 8))

    STAGE_V(0, 0);
    short8 kpa0 = LDK(0, 0, 0), kpa1 = LDK(0, 0, 1);
    short8 kpb0 = LDK(0, 1, 0), kpb1 = LDK(0, 1, 1);
    int cur = 0;

    for (int t0 = 0; t0 < SEQ; t0 += KVB) {
        __syncthreads();            // stage(cur) complete

        // swapped QK^T: sc[nb][r] = S[kv = t0+nb*16+lg*4+r][q = qbase+l15]
        f32x4 sc[4];
        __builtin_amdgcn_s_setprio(1);
        sc[0] = __builtin_amdgcn_mfma_f32_16x16x32_bf16(kpa0, qf[0], zero, 0, 0, 0);
        sc[0] = __builtin_amdgcn_mfma_f32_16x16x32_bf16(kpa1, qf[1], sc[0], 0, 0, 0);
        sc[1] = __builtin_amdgcn_mfma_f32_16x16x32_bf16(kpb0, qf[0], zero, 0, 0, 0);
        sc[1] = __builtin_amdgcn_mfma_f32_16x16x32_bf16(kpb1, qf[1], sc[1], 0, 0, 0);
        __builtin_amdgcn_s_setprio(0);
        {
            short8 k20 = LDK(t0, 2, 0), k21 = LDK(t0, 2, 1);
            short8 k30 = LDK(t0, 3, 0), k31 = LDK(t0, 3, 1);
            sc[2] = __builtin_amdgcn_mfma_f32_16x16x32_bf16(k20, qf[0], zero, 0, 0, 0);
            sc[2] = __builtin_amdgcn_mfma_f32_16x16x32_bf16(k21, qf[1], sc[2], 0, 0, 0);
            sc[3] = __builtin_amdgcn_mfma_f32_16x16x32_bf16(k30, qf[0], zero, 0, 0, 0);
            sc[3] = __builtin_amdgcn_mfma_f32_16x16x32_bf16(k31, qf[1], sc[3], 0, 0, 0);
        }

        if (t0 + KVB < SEQ) {       // prefetch next V tile + next K nb=0,1
            STAGE_V(t0 + KVB, cur ^ 1);
            kpa0 = LDK(t0 + KVB, 0, 0); kpa1 = LDK(t0 + KVB, 0, 1);
            kpb0 = LDK(t0 + KVB, 1, 0); kpb1 = LDK(t0 + KVB, 1, 1);
        }

        // lane-local row max over own 16 scores (all belong to q = l15)
        float lm = fmaxf(
            fmaxf(fmaxf(fmaxf(sc[0][0], sc[0][1]), fmaxf(sc[0][2], sc[0][3])),
                  fmaxf(fmaxf(sc[1][0], sc[1][1]), fmaxf(sc[1][2], sc[1][3]))),
            fmaxf(fmaxf(fmaxf(sc[2][0], sc[2][1]), fmaxf(sc[2][2], sc[2][3])),
                  fmaxf(fmaxf(sc[3][0], sc[3][1]), fmaxf(sc[3][2], sc[3][3]))));
        if (__any(lm - m_own > 8.f)) {
            float rv = fmaxf(lm, __shfl_xor(lm, 16));
            rv = fmaxf(rv, __shfl_xor(rv, 32));
            float mnew = fmaxf(m_own, rv);
            float fac = exp2f(m_own - mnew);
            m_own = mnew;
#pragma unroll
            for (int r = 0; r < 4; ++r) {
                float fr = __shfl(fac, lg * 4 + r);   // fac for output row q=lg*4+r
                o1[r] *= fr;
#pragma unroll
                for (int db = 0; db < 4; ++db) o[db][r] *= fr;
            }
        }

        // P = exp2(sc - m), pack pairs (adjacent kv), store b32 swizzled
#pragma unroll
        for (int nb = 0; nb < 4; ++nb) {
            float p0 = exp2f(sc[nb][0] - m_own);
            float p1 = exp2f(sc[nb][1] - m_own);
            float p2 = exp2f(sc[nb][2] - m_own);
            float p3 = exp2f(sc[nb][3] - m_own);
            u32 pk01 = __builtin_amdgcn_perm(__builtin_bit_cast(u32, p1),
                                             __builtin_bit_cast(u32, p0),
                                             0x07060302u);
            u32 pk23 = __builtin_amdgcn_perm(__builtin_bit_cast(u32, p3),
                                             __builtin_bit_cast(u32, p2),
                                             0x07060302u);
            int ck = (nb * 2 + (lg >> 1)) ^ psw;
            u32* dst = (u32*)(Pu + l15 * 64 + ck * 8) + (lg & 1) * 2;
            dst[0] = pk01;
            dst[1] = pk23;
        }

        // PV + ones-row sums
        short8 pa[2];
#pragma unroll
        for (int ts = 0; ts < 2; ++ts)
            pa[ts] = *(const short8*)(Pu + l15 * 64 + (((ts * 4 + lg) ^ psw) * 8));
        __builtin_amdgcn_s_setprio(1);
#pragma unroll
        for (int db = 0; db < 4; ++db) {
            const int d = db * 16 + l15;
#pragma unroll
            for (int ts = 0; ts < 2; ++ts) {
                short8 vb = *(const short8*)((const char*)Vt[cur] + d * 128 +
                                             (((ts * 4 + lg) ^ psw) << 4));
                o[db] = __builtin_amdgcn_mfma_f32_16x16x32_bf16(pa[ts], vb, o[db], 0, 0, 0);
            }
        }
        o1 = __builtin_amdgcn_mfma_f32_16x16x32_bf16(pa[0], onesf, o1, 0, 0, 0);
        o1 = __builtin_amdgcn_mfma_f32_16x16x32_bf16(pa[1], onesf, o1, 0, 0, 0);
        __builtin_amdgcn_s_setprio(0);
        cur ^= 1;
    }

    const int b = bh >> 4, h = bh & 15;
#pragma unroll
    for (int r = 0; r < 4; ++r) {
        float inv = 1.0f / o1[r];
        int srow = qbase + lg * 4 + r;
        size_t rowoff = ((size_t)(b * SEQ + srow)) * D_MODEL + h * DK;
#pragma unroll
        for (int db = 0; db < 4; ++db)
            ctx[rowoff + db * 16 + l15] = f2bf(o[db][r] * inv);
    }
#undef STAGE_V
#undef LDK
}

// ---------------- fused residual + LayerNorm (optional second residual input) ----------------
__global__ __launch_bounds__(256) void ln_res(const float* __restrict__ X,
                                              const float* __restrict__ Y,
                                              const float* __restrict__ Y2,
                                              const float* __restrict__ gamma,
                                              const float* __restrict__ beta,
                                              float* __restrict__ outf,
                                              u16* __restrict__ outb) {
    __shared__ float red[8];
    const int row = blockIdx.x, t = threadIdx.x;
    const size_t off = (size_t)row * D_MODEL + t * 4;
    float4 xv = *(const float4*)(X + off);
    float4 yv = *(const float4*)(Y + off);
    float sx = xv.x + yv.x, sy = xv.y + yv.y, sz = xv.z + yv.z, sw = xv.w + yv.w;
    if (Y2) {
        float4 y2 = *(const float4*)(Y2 + off);
        sx += y2.x; sy += y2.y; sz += y2.z; sw += y2.w;
    }
    float ps = sx + sy + sz + sw;
#pragma unroll
    for (int o2 = 32; o2; o2 >>= 1) ps += __shfl_xor(ps, o2);
    if ((t & 63) == 0) red[t >> 6] = ps;
    __syncthreads();
    float mu = (red[0] + red[1] + red[2] + red[3]) * (1.0f / D_MODEL);
    float d0 = sx - mu, d1 = sy - mu, d2 = sz - mu, d3 = sw - mu;
    float p2 = d0 * d0 + d1 * d1 + d2 * d2 + d3 * d3;
#pragma unroll
    for (int o2 = 32; o2; o2 >>= 1) p2 += __shfl_xor(p2, o2);
    if ((t & 63) == 0) red[4 + (t >> 6)] = p2;
    __syncthreads();
    float var = (red[4] + red[5] + red[6] + red[7]) * (1.0f / D_MODEL);
    float rstd = rsqrtf(var + 1e-5f);
    float4 gv = *(const float4*)(gamma + t * 4);
    float4 bv = *(const float4*)(beta + t * 4);
    float r0 = d0 * rstd * gv.x + bv.x;
    float r1 = d1 * rstd * gv.y + bv.y;
    float r2 = d2 * rstd * gv.z + bv.z;
    float r3 = d3 * rstd * gv.w + bv.w;
    float4 res; res.x = r0; res.y = r1; res.z = r2; res.w = r3;
    *(float4*)(outf + off) = res;
    if (outb) {
        outb[off + 0] = f2bf(r0);
        outb[off + 1] = f2bf(r1);
        outb[off + 2] = f2bf(r2);
        outb[off + 3] = f2bf(r3);
    }
}

extern "C" void kernel_launch(void* const* d_in, const int* in_sizes, int n_in,
                              void* d_out, int out_size, void* d_ws, size_t ws_size,
                              hipStream_t stream) {
    (void)in_sizes; (void)n_in; (void)out_size; (void)ws_size;
    const float* x  = (const float*)d_in[0];
    const float* Wq = (const float*)d_in[1];
    const float* bq = (const float*)d_in[2];
    const float* Wk = (const float*)d_in[3];
    const float* bk = (const float*)d_in[4];
    const float* Wv = (const float*)d_in[5];
    const float* bv = (const float*)d_in[6];
    const float* Wo = (const float*)d_in[7];
    const float* bo = (const float*)d_in[8];
    const float* W1 = (const float*)d_in[9];
    const float* b1 = (const float*)d_in[10];
    const float* W2 = (const float*)d_in[11];
    const float* b2 = (const float*)d_in[12];
    const float* g1 = (const float*)d_in[13];
    const float* be1 = (const float*)d_in[14];
    const float* g2 = (const float*)d_in[15];
    const float* be2 = (const float*)d_in[16];

    char* ws = (char*)d_ws;                         // 96 MB total, overlapped
    u16* xb   = (u16*)(ws);                         // 8 MB : x bf16, then ctx, then Fs2(lo)
    u16* Qb   = (u16*)(ws + ((size_t)8 << 20));     // 8 MB : Q, then W1b, then Fs2(hi)
    u16* Kb   = (u16*)(ws + ((size_t)16 << 20));    // 8 MB : K, then W2b
    u16* Vb   = (u16*)(ws + ((size_t)24 << 20));    // 8 MB : V, then x1b
    float* x1 = (float*)(ws + ((size_t)32 << 20));  // 16 MB
    float* Fs = (float*)(ws + ((size_t)48 << 20));  // 16 MB : V^T, then attn_out/ff
    u16* hb   = (u16*)(ws + ((size_t)64 << 20));    // 32 MB : weights bf16, then h
    u16* Wqb = hb;
    u16* Wkb = hb + (1u << 20);
    u16* Wvb = hb + (2u << 20);
    u16* Wob = hb + (3u << 20);
    u16* W1b = Qb;
    u16* W2b = Kb;
    u16* Vtg = (u16*)Fs;                            // 8 MB V^T (dead before Wo out)
    u16* ctxb = xb;
    u16* x1b  = Vb;
    float* Fs2 = (float*)ws;                        // 16 MB (xb+Qb slots, dead during W2)

    // 1. convert x and the 4 d*d weights to bf16
    cvt_bf16<<<dim3(NTOK * D_MODEL / 1024), 256, 0, stream>>>(x, xb);
    cvt_bf16_4<<<dim3(4096), 256, 0, stream>>>(Wq, Wk, Wv, Wo,
                                               Wqb, Wkb, Wvb, Wob);

    // 2. fused QKV projections (Q pre-scaled by 1/sqrt(dk) * log2e)
    gemm_qkv<<<dim3(24, 32), 256, 0, stream>>>(xb, Wqb, Wkb, Wvb, bq, bk, bv,
                                               Qb, Kb, Vb);

    // 3. V -> V^T (pre-swizzled)
    transpose_v<<<dim3(SEQ / 128, 32), 256, 0, stream>>>(Vb, Vtg);

    // 4. attention -> ctx (reuses xb)
    attn_fwd<<<dim3(SEQ / 64, 32), 256, 0, stream>>>(Qb, Kb, Vtg, ctxb);

    // 5. convert FFN weights into now-dead Q/K slots
    cvt_bf16_2<<<dim3(8192), 256, 0, stream>>>(W1, W2, W1b, W2b);

    // 6. output projection -> Fs (fp32)
    gemm_k64<<<dim3(8, 64, 1), 256, 0, stream>>>(ctxb, Wob, bo, Fs, nullptr,
                                                 NTOK, D_MODEL, D_MODEL);

    // 7. x1 = LN(x + attn_out)
    ln_res<<<dim3(NTOK), 256, 0, stream>>>(x, Fs, nullptr, g1, be1, x1, x1b);

    // 8. h = relu(x1 @ W1^T + b1)
    gemm_bt64<1><<<dim3(32, 32), 256, 0, stream>>>(
        x1b, W1b, b1, hb, nullptr, NTOK, DFF, D_MODEL);

    // 9. ff = h @ W2^T + b2 -> Fs + Fs2 (split-K x2)
    gemm_k64<<<dim3(8, 64, 2), 256, 0, stream>>>(hb, W2b, b2, Fs, Fs2,
                                                 NTOK, D_MODEL, DFF);

    // 10. out = LN(x1 + ffA + ffB)
    ln_res<<<dim3(NTOK), 256, 0, stream>>>(x1, Fs, Fs2, g2, be2,
                                           (float*)d_out, nullptr);
}

// Round 6
// 297.285 us; speedup vs baseline: 1.1996x; 1.1996x over previous
//
#include <hip/hip_runtime.h>

typedef unsigned short u16;
typedef unsigned int u32;
typedef __attribute__((ext_vector_type(8))) short short8;
typedef __attribute__((ext_vector_type(4))) float f32x4;

#define D_MODEL 1024
#define SEQ 2048
#define NH 16
#define DK 64
#define DFF 4096
#define NTOK 4096
#define LOG2E 1.44269504f

__device__ __forceinline__ u16 f2bf(float f) {
    unsigned x = __builtin_bit_cast(unsigned, f);
    x = x + 0x7fffu + ((x >> 16) & 1u);
    return (u16)(x >> 16);
}

__device__ __forceinline__ void gload_lds16(const void* g, void* l) {
    __builtin_amdgcn_global_load_lds(
        (__attribute__((address_space(1))) void*)g,
        (__attribute__((address_space(3))) void*)l, 16, 0, 0);
}

// ---------------- fp32 -> bf16 converts ----------------
__device__ __forceinline__ void cvt_body(const float* __restrict__ in,
                                         u16* __restrict__ out, int blk) {
    size_t i = ((size_t)blk * 256 + threadIdx.x) * 4;
    float4 v = *(const float4*)(in + i);
    out[i + 0] = f2bf(v.x);
    out[i + 1] = f2bf(v.y);
    out[i + 2] = f2bf(v.z);
    out[i + 3] = f2bf(v.w);
}

__global__ __launch_bounds__(256) void cvt_bf16(const float* __restrict__ in,
                                                u16* __restrict__ out) {
    cvt_body(in, out, blockIdx.x);
}

__global__ __launch_bounds__(256) void cvt_bf16_4(
    const float* __restrict__ s0, const float* __restrict__ s1,
    const float* __restrict__ s2, const float* __restrict__ s3,
    u16* __restrict__ d0, u16* __restrict__ d1, u16* __restrict__ d2,
    u16* __restrict__ d3) {
    int which = blockIdx.x >> 10, blk = blockIdx.x & 1023;
    const float* s = which == 0 ? s0 : which == 1 ? s1 : which == 2 ? s2 : s3;
    u16* d = which == 0 ? d0 : which == 1 ? d1 : which == 2 ? d2 : d3;
    cvt_body(s, d, blk);
}

__global__ __launch_bounds__(256) void cvt_bf16_2(
    const float* __restrict__ s0, const float* __restrict__ s1,
    u16* __restrict__ d0, u16* __restrict__ d1) {
    int which = blockIdx.x >> 12, blk = blockIdx.x & 4095;
    cvt_body(which ? s1 : s0, which ? d1 : d0, blk);
}

// ---------------- V transpose: [b,h,s,d] -> [b,h,d,s], pre-swizzled ----------------
__global__ __launch_bounds__(256) void transpose_v(const u16* __restrict__ V,
                                                   u16* __restrict__ Vt) {
    __shared__ u16 T[128 * 65];
    const int tid = threadIdx.x;
    const int bh = blockIdx.y;
    const int s0 = blockIdx.x * 128;
    const size_t base = (size_t)bh * SEQ * DK;
#pragma unroll
    for (int j = 0; j < 4; ++j) {
        int c = j * 256 + tid;
        int s = c >> 3, dc = c & 7;
        short8 v = *(const short8*)(V + base + (size_t)(s0 + s) * DK + dc * 8);
#pragma unroll
        for (int e = 0; e < 8; ++e) T[s * 65 + dc * 8 + e] = (u16)v[e];
    }
    __syncthreads();
    const size_t obase = (size_t)bh * DK * SEQ;
#pragma unroll
    for (int j = 0; j < 4; ++j) {
        int c = j * 256 + tid;
        int d = c >> 4, tc = c & 15;
        short8 v;
#pragma unroll
        for (int e = 0; e < 8; ++e) v[e] = (short)T[(tc * 8 + e) * 65 + d];
        *(short8*)(Vt + obase + (size_t)d * SEQ + s0 + ((tc ^ (d & 7)) * 8)) = v;
    }
}

// ---------------- GEMM core: acc += A[M,K](bf16) @ W[N,K](bf16)^T, m97-style, BK=32 ----------------
template <int BM, int BN>
__device__ __forceinline__ void gemm_acc(const u16* __restrict__ A,
                                         const u16* __restrict__ W,
                                         int K, int m0, int n0,
                                         f32x4 (&acc)[BM / 32][BN / 32]) {
    constexpr int MR = BM / 32, NR = BN / 32;
    __shared__ short8 As[BM][4];
    __shared__ short8 Bs[BN][4];
    const int tid = threadIdx.x;
    const int lane = tid & 63, w = tid >> 6;
    const int l15 = lane & 15, lg = lane >> 4;
    const int wr = (w >> 1) * (BM / 2), wc = (w & 1) * (BN / 2);

#pragma unroll
    for (int i = 0; i < MR; ++i)
#pragma unroll
        for (int j = 0; j < NR; ++j) acc[i][j] = (f32x4){0.f, 0.f, 0.f, 0.f};

    for (int k0 = 0; k0 < K; k0 += 32) {
        __syncthreads();
#pragma unroll
        for (int j = 0; j < BM / 64; ++j) {
            int idx = j * 256 + tid;
            gload_lds16(A + (size_t)(m0 + (idx >> 2)) * K + k0 + (idx & 3) * 8,
                        (char*)As + (j * 256 + w * 64) * 16);
        }
#pragma unroll
        for (int j = 0; j < BN / 64; ++j) {
            int idx = j * 256 + tid;
            gload_lds16(W + (size_t)(n0 + (idx >> 2)) * K + k0 + (idx & 3) * 8,
                        (char*)Bs + (j * 256 + w * 64) * 16);
        }
        __syncthreads();

        short8 af[MR], bf[NR];
#pragma unroll
        for (int m = 0; m < MR; ++m) af[m] = As[wr + m * 16 + l15][lg];
#pragma unroll
        for (int n = 0; n < NR; ++n) bf[n] = Bs[wc + n * 16 + l15][lg];
#pragma unroll
        for (int m = 0; m < MR; ++m)
#pragma unroll
            for (int n = 0; n < NR; ++n)
                acc[m][n] = __builtin_amdgcn_mfma_f32_16x16x32_bf16(
                    af[m], bf[n], acc[m][n], 0, 0, 0);
    }
}

// EPI 0: fp32 out row-major; EPI 1: relu bf16 row-major
template <int BM, int BN, int EPI>
__global__ __launch_bounds__(256) void gemm_bt(
    const u16* __restrict__ A, const u16* __restrict__ W,
    const float* __restrict__ bias, u16* __restrict__ outb,
    float* __restrict__ outf, int M, int N, int K) {
    f32x4 acc[BM / 32][BN / 32];
    const int m0 = blockIdx.y * BM, n0 = blockIdx.x * BN;
    gemm_acc<BM, BN>(A, W, K, m0, n0, acc);
    const int lane = threadIdx.x & 63, w = threadIdx.x >> 6;
    const int l15 = lane & 15, lg = lane >> 4;
    const int wr = (w >> 1) * (BM / 2), wc = (w & 1) * (BN / 2);
#pragma unroll
    for (int m = 0; m < BM / 32; ++m)
#pragma unroll
        for (int n = 0; n < BN / 32; ++n) {
            int gn = n0 + wc + n * 16 + l15;
            float bv = bias[gn];
#pragma unroll
            for (int r = 0; r < 4; ++r) {
                int gm = m0 + wr + m * 16 + lg * 4 + r;
                float v = acc[m][n][r] + bv;
                if (EPI == 0) outf[(size_t)gm * N + gn] = v;
                else outb[(size_t)gm * N + gn] = f2bf(fmaxf(v, 0.f));
            }
        }
}

// ---------------- 64x128 tile, BK=64 GEMM (fp32 out) for N=1024 shapes ----------------
__global__ __launch_bounds__(256) void gemm_k64(
    const u16* __restrict__ A, const u16* __restrict__ W,
    const float* __restrict__ bias, float* __restrict__ outf,
    int M, int N, int K) {
    __shared__ short8 As[64][8];
    __shared__ short8 Bs[128][8];
    const int tid = threadIdx.x;
    const int lane = tid & 63, w = tid >> 6;
    const int l15 = lane & 15, lg = lane >> 4;
    const int wr = (w >> 1) * 32, wc = (w & 1) * 64;
    const int m0 = blockIdx.y * 64, n0 = blockIdx.x * 128;

    f32x4 acc[2][4];
#pragma unroll
    for (int i = 0; i < 2; ++i)
#pragma unroll
        for (int j = 0; j < 4; ++j) acc[i][j] = (f32x4){0.f, 0.f, 0.f, 0.f};

    for (int k0 = 0; k0 < K; k0 += 64) {
        __syncthreads();
#pragma unroll
        for (int j = 0; j < 2; ++j) {
            int idx = j * 256 + tid;
            gload_lds16(A + (size_t)(m0 + (idx >> 3)) * K + k0 + (idx & 7) * 8,
                        (char*)As + (j * 256 + w * 64) * 16);
        }
#pragma unroll
        for (int j = 0; j < 4; ++j) {
            int idx = j * 256 + tid;
            gload_lds16(W + (size_t)(n0 + (idx >> 3)) * K + k0 + (idx & 7) * 8,
                        (char*)Bs + (j * 256 + w * 64) * 16);
        }
        __syncthreads();

#pragma unroll
        for (int kk = 0; kk < 2; ++kk) {
            short8 af[2], bf[4];
#pragma unroll
            for (int m = 0; m < 2; ++m) af[m] = As[wr + m * 16 + l15][kk * 4 + lg];
#pragma unroll
            for (int n = 0; n < 4; ++n) bf[n] = Bs[wc + n * 16 + l15][kk * 4 + lg];
#pragma unroll
            for (int m = 0; m < 2; ++m)
#pragma unroll
                for (int n = 0; n < 4; ++n)
                    acc[m][n] = __builtin_amdgcn_mfma_f32_16x16x32_bf16(
                        af[m], bf[n], acc[m][n], 0, 0, 0);
        }
    }

#pragma unroll
    for (int m = 0; m < 2; ++m)
#pragma unroll
        for (int n = 0; n < 4; ++n) {
            int gn = n0 + wc + n * 16 + l15;
            float bv = bias[gn];
#pragma unroll
            for (int r = 0; r < 4; ++r) {
                int gm = m0 + wr + m * 16 + lg * 4 + r;
                outf[(size_t)gm * N + gn] = acc[m][n][r] + bv;
            }
        }
}

// fused QKV: blockIdx.x selects matrix; out in [B,H,S,dk], Q pre-scaled
__global__ __launch_bounds__(256) void gemm_qkv(
    const u16* __restrict__ A, const u16* __restrict__ Wq,
    const u16* __restrict__ Wk, const u16* __restrict__ Wv,
    const float* __restrict__ bq, const float* __restrict__ bk,
    const float* __restrict__ bv, u16* __restrict__ Qo, u16* __restrict__ Ko,
    u16* __restrict__ Vo) {
    const int mat = blockIdx.x >> 3;
    const u16* W = mat == 0 ? Wq : (mat == 1 ? Wk : Wv);
    const float* bias = mat == 0 ? bq : (mat == 1 ? bk : bv);
    u16* out = mat == 0 ? Qo : (mat == 1 ? Ko : Vo);
    const float scale = (mat == 0) ? 0.125f * LOG2E : 1.0f;
    f32x4 acc[4][4];
    const int m0 = blockIdx.y * 128, n0 = (blockIdx.x & 7) * 128;
    gemm_acc<128, 128>(A, W, D_MODEL, m0, n0, acc);
    const int lane = threadIdx.x & 63, w = threadIdx.x >> 6;
    const int l15 = lane & 15, lg = lane >> 4;
    const int wr = (w >> 1) * 64, wc = (w & 1) * 64;
#pragma unroll
    for (int m = 0; m < 4; ++m)
#pragma unroll
        for (int n = 0; n < 4; ++n) {
            int gn = n0 + wc + n * 16 + l15;
            float bv = bias[gn];
            int h = gn >> 6, d = gn & 63;
#pragma unroll
            for (int r = 0; r < 4; ++r) {
                int gm = m0 + wr + m * 16 + lg * 4 + r;
                int b = gm >> 11, s = gm & 2047;
                float v = (acc[m][n][r] + bv) * scale;
                out[(((size_t)(b * NH + h)) * SEQ + s) * DK + d] = f2bf(v);
            }
        }
}

// ---------------- flash attention: K+V both LDS-staged (dbuf), swapped QK^T, ones-MFMA sums ----------------
#define KVB 64
__global__ __launch_bounds__(256) void attn_fwd(const u16* __restrict__ Q,
                                                const u16* __restrict__ Kp,
                                                const u16* __restrict__ Vg_,
                                                u16* __restrict__ ctx) {
    __shared__ __align__(16) u16 Kt[2][64 * 64];    // swizzled [kv][d], 8KB each
    __shared__ __align__(16) u16 Vt[2][64 * 64];    // swizzled [d][t], 8KB each
    __shared__ __align__(16) u16 Ps[4][16 * 64];    // per-wave [q][kv]

    const int tid = threadIdx.x;
    const int lane = tid & 63;
    const int w = tid >> 6;
    const int l15 = lane & 15;
    const int lg = lane >> 4;
    // XCD grouping: all 32 q-blocks of one head share an XCD's L2
    const int f = blockIdx.x + 32 * blockIdx.y;
    const int bh = f & 31;
    const int qblk = f >> 5;
    const int qbase = qblk * 64 + w * 16;
    const u16* Qb = Q + (size_t)bh * SEQ * DK;
    const u16* Kb = Kp + (size_t)bh * SEQ * DK;
    const u16* Vg = Vg_ + (size_t)bh * DK * SEQ;    // [d][s] pre-swizzled

    short8 qf[2];
#pragma unroll
    for (int hf = 0; hf < 2; ++hf)
        qf[hf] = *(const short8*)(Qb + (size_t)(qbase + l15) * DK + hf * 32 + lg * 8);

    short8 onesf;
#pragma unroll
    for (int e = 0; e < 8; ++e) onesf[e] = (short)0x3F80;  // bf16 1.0

    f32x4 zero = {0.f, 0.f, 0.f, 0.f};
    f32x4 o[4], o1 = zero;
#pragma unroll
    for (int db = 0; db < 4; ++db) o[db] = zero;
    float m_own = -1e30f;                            // running max for q = l15

    u16* Pu = Ps[w];
    const int psw = l15 & 7;

#define STAGE_V(T0, BUF)                                                       \
    {                                                                          \
        _Pragma("unroll") for (int j = 0; j < 2; ++j) {                        \
            int idx = j * 256 + tid;                                           \
            gload_lds16(Vg + (size_t)(idx >> 3) * SEQ + (T0) + (idx & 7) * 8,  \
                        (char*)Vt[BUF] + (j * 256 + w * 64) * 16);             \
        }                                                                      \
    }
    // K: linear LDS dest; swizzle rides on the per-lane GLOBAL source address
#define STAGE_K(T0, BUF)                                                       \
    {                                                                          \
        _Pragma("unroll") for (int j = 0; j < 2; ++j) {                        \
            int idx = j * 256 + tid;                                           \
            int kv = idx >> 3, ck = idx & 7;                                   \
            gload_lds16(Kb + (size_t)((T0) + kv) * DK + ((ck ^ (kv & 7)) * 8), \
                        (char*)Kt[BUF] + (j * 256 + w * 64) * 16);             \
        }                                                                      \
    }
#define KF(BUF, NB, HALF)                                                      \
    (*(const short8*)((const char*)Kt[BUF] + ((NB)*16 + l15) * 128 +           \
                      (((((HALF)*4 + lg)) ^ psw) << 4)))

    STAGE_K(0, 0);
    STAGE_V(0, 0);
    int cur = 0;

    for (int t0 = 0; t0 < SEQ; t0 += KVB) {
        __syncthreads();            // stage(cur) complete; prev readers done

        if (t0 + KVB < SEQ) {       // prefetch next tile (latency hidden under compute)
            STAGE_K(t0 + KVB, cur ^ 1);
            STAGE_V(t0 + KVB, cur ^ 1);
        }

        // swapped QK^T: sc[nb][r] = S[kv = t0+nb*16+lg*4+r][q = qbase+l15]
        f32x4 sc[4];
        __builtin_amdgcn_s_setprio(1);
#pragma unroll
        for (int nb = 0; nb < 4; ++nb) {
            sc[nb] = __builtin_amdgcn_mfma_f32_16x16x32_bf16(KF(cur, nb, 0), qf[0],
                                                             zero, 0, 0, 0);
            sc[nb] = __builtin_amdgcn_mfma_f32_16x16x32_bf16(KF(cur, nb, 1), qf[1],
                                                             sc[nb], 0, 0, 0);
        }
        __builtin_amdgcn_s_setprio(0);

        // lane-local row max over own 16 scores (all belong to q = l15)
        float lm = fmaxf(
            fmaxf(fmaxf(fmaxf(sc[0][0], sc[0][1]), fmaxf(sc[0][2], sc[0][3])),
                  fmaxf(fmaxf(sc[1][0], sc[1][1]), fmaxf(sc[1][2], sc[1][3]))),
            fmaxf(fmaxf(fmaxf(sc[2][0], sc[2][1]), fmaxf(sc[2][2], sc[2][3])),
                  fmaxf(fmaxf(sc[3][0], sc[3][1]), fmaxf(sc[3][2], sc[3][3]))));
        if (__any(lm - m_own > 8.f)) {
            float rv = fmaxf(lm, __shfl_xor(lm, 16));
            rv = fmaxf(rv, __shfl_xor(rv, 32));
            float mnew = fmaxf(m_own, rv);
            float fac = exp2f(m_own - mnew);
            m_own = mnew;
#pragma unroll
            for (int r = 0; r < 4; ++r) {
                float fr = __shfl(fac, lg * 4 + r);   // fac for output row q=lg*4+r
                o1[r] *= fr;
#pragma unroll
                for (int db = 0; db < 4; ++db) o[db][r] *= fr;
            }
        }

        // P = exp2(sc - m), pack pairs (adjacent kv), store b32 swizzled
#pragma unroll
        for (int nb = 0; nb < 4; ++nb) {
            float p0 = exp2f(sc[nb][0] - m_own);
            float p1 = exp2f(sc[nb][1] - m_own);
            float p2 = exp2f(sc[nb][2] - m_own);
            float p3 = exp2f(sc[nb][3] - m_own);
            u32 pk01 = __builtin_amdgcn_perm(__builtin_bit_cast(u32, p1),
                                             __builtin_bit_cast(u32, p0),
                                             0x07060302u);
            u32 pk23 = __builtin_amdgcn_perm(__builtin_bit_cast(u32, p3),
                                             __builtin_bit_cast(u32, p2),
                                             0x07060302u);
            int ck = (nb * 2 + (lg >> 1)) ^ psw;
            u32* dst = (u32*)(Pu + l15 * 64 + ck * 8) + (lg & 1) * 2;
            dst[0] = pk01;
            dst[1] = pk23;
        }

        // PV + ones-row sums
        short8 pa[2];
#pragma unroll
        for (int ts = 0; ts < 2; ++ts)
            pa[ts] = *(const short8*)(Pu + l15 * 64 + (((ts * 4 + lg) ^ psw) * 8));
        __builtin_amdgcn_s_setprio(1);
#pragma unroll
        for (int db = 0; db < 4; ++db) {
            const int d = db * 16 + l15;
#pragma unroll
            for (int ts = 0; ts < 2; ++ts) {
                short8 vb = *(const short8*)((const char*)Vt[cur] + d * 128 +
                                             (((ts * 4 + lg) ^ psw) << 4));
                o[db] = __builtin_amdgcn_mfma_f32_16x16x32_bf16(pa[ts], vb, o[db], 0, 0, 0);
            }
        }
        o1 = __builtin_amdgcn_mfma_f32_16x16x32_bf16(pa[0], onesf, o1, 0, 0, 0);
        o1 = __builtin_amdgcn_mfma_f32_16x16x32_bf16(pa[1], onesf, o1, 0, 0, 0);
        __builtin_amdgcn_s_setprio(0);
        cur ^= 1;
    }

    const int b = bh >> 4, h = bh & 15;
#pragma unroll
    for (int r = 0; r < 4; ++r) {
        float inv = 1.0f / o1[r];
        int srow = qbase + lg * 4 + r;
        size_t rowoff = ((size_t)(b * SEQ + srow)) * D_MODEL + h * DK;
#pragma unroll
        for (int db = 0; db < 4; ++db)
            ctx[rowoff + db * 16 + l15] = f2bf(o[db][r] * inv);
    }
#undef STAGE_V
#undef STAGE_K
#undef KF
}

// ---------------- fused residual + LayerNorm ----------------
__global__ __launch_bounds__(256) void ln_res(const float* __restrict__ X,
                                              const float* __restrict__ Y,
                                              const float* __restrict__ gamma,
                                              const float* __restrict__ beta,
                                              float* __restrict__ outf,
                                              u16* __restrict__ outb) {
    __shared__ float red[8];
    const int row = blockIdx.x, t = threadIdx.x;
    const size_t off = (size_t)row * D_MODEL + t * 4;
    float4 xv = *(const float4*)(X + off);
    float4 yv = *(const float4*)(Y + off);
    float sx = xv.x + yv.x, sy = xv.y + yv.y, sz = xv.z + yv.z, sw = xv.w + yv.w;
    float ps = sx + sy + sz + sw;
#pragma unroll
    for (int o2 = 32; o2; o2 >>= 1) ps += __shfl_xor(ps, o2);
    if ((t & 63) == 0) red[t >> 6] = ps;
    __syncthreads();
    float mu = (red[0] + red[1] + red[2] + red[3]) * (1.0f / D_MODEL);
    float d0 = sx - mu, d1 = sy - mu, d2 = sz - mu, d3 = sw - mu;
    float p2 = d0 * d0 + d1 * d1 + d2 * d2 + d3 * d3;
#pragma unroll
    for (int o2 = 32; o2; o2 >>= 1) p2 += __shfl_xor(p2, o2);
    if ((t & 63) == 0) red[4 + (t >> 6)] = p2;
    __syncthreads();
    float var = (red[4] + red[5] + red[6] + red[7]) * (1.0f / D_MODEL);
    float rstd = rsqrtf(var + 1e-5f);
    float4 gv = *(const float4*)(gamma + t * 4);
    float4 bv = *(const float4*)(beta + t * 4);
    float r0 = d0 * rstd * gv.x + bv.x;
    float r1 = d1 * rstd * gv.y + bv.y;
    float r2 = d2 * rstd * gv.z + bv.z;
    float r3 = d3 * rstd * gv.w + bv.w;
    float4 res; res.x = r0; res.y = r1; res.z = r2; res.w = r3;
    *(float4*)(outf + off) = res;
    if (outb) {
        outb[off + 0] = f2bf(r0);
        outb[off + 1] = f2bf(r1);
        outb[off + 2] = f2bf(r2);
        outb[off + 3] = f2bf(r3);
    }
}

extern "C" void kernel_launch(void* const* d_in, const int* in_sizes, int n_in,
                              void* d_out, int out_size, void* d_ws, size_t ws_size,
                              hipStream_t stream) {
    (void)in_sizes; (void)n_in; (void)out_size; (void)ws_size;
    const float* x  = (const float*)d_in[0];
    const float* Wq = (const float*)d_in[1];
    const float* bq = (const float*)d_in[2];
    const float* Wk = (const float*)d_in[3];
    const float* bk = (const float*)d_in[4];
    const float* Wv = (const float*)d_in[5];
    const float* bv = (const float*)d_in[6];
    const float* Wo = (const float*)d_in[7];
    const float* bo = (const float*)d_in[8];
    const float* W1 = (const float*)d_in[9];
    const float* b1 = (const float*)d_in[10];
    const float* W2 = (const float*)d_in[11];
    const float* b2 = (const float*)d_in[12];
    const float* g1 = (const float*)d_in[13];
    const float* be1 = (const float*)d_in[14];
    const float* g2 = (const float*)d_in[15];
    const float* be2 = (const float*)d_in[16];

    char* ws = (char*)d_ws;                         // 96 MB total, overlapped
    u16* xb   = (u16*)(ws);                         // 8 MB : x bf16, then ctx
    u16* Qb   = (u16*)(ws + ((size_t)8 << 20));     // 8 MB : Q, then W1b
    u16* Kb   = (u16*)(ws + ((size_t)16 << 20));    // 8 MB : K, then W2b
    u16* Vb   = (u16*)(ws + ((size_t)24 << 20));    // 8 MB : V, then x1b
    float* x1 = (float*)(ws + ((size_t)32 << 20));  // 16 MB
    float* Fs = (float*)(ws + ((size_t)48 << 20));  // 16 MB : V^T, then attn_out/ff
    u16* hb   = (u16*)(ws + ((size_t)64 << 20));    // 32 MB : weights bf16, then h
    u16* Wqb = hb;
    u16* Wkb = hb + (1u << 20);
    u16* Wvb = hb + (2u << 20);
    u16* Wob = hb + (3u << 20);
    u16* W1b = Qb;
    u16* W2b = Kb;
    u16* Vtg = (u16*)Fs;                            // 8 MB V^T (dead before Wo out)
    u16* ctxb = xb;
    u16* x1b  = Vb;

    // 1. convert x and the 4 d*d weights to bf16
    cvt_bf16<<<dim3(NTOK * D_MODEL / 1024), 256, 0, stream>>>(x, xb);
    cvt_bf16_4<<<dim3(4096), 256, 0, stream>>>(Wq, Wk, Wv, Wo,
                                               Wqb, Wkb, Wvb, Wob);

    // 2. fused QKV projections (Q pre-scaled by 1/sqrt(dk) * log2e)
    gemm_qkv<<<dim3(24, 32), 256, 0, stream>>>(xb, Wqb, Wkb, Wvb, bq, bk, bv,
                                               Qb, Kb, Vb);

    // 3. V -> V^T (pre-swizzled)
    transpose_v<<<dim3(SEQ / 128, 32), 256, 0, stream>>>(Vb, Vtg);

    // 4. attention -> ctx (reuses xb)
    attn_fwd<<<dim3(SEQ / 64, 32), 256, 0, stream>>>(Qb, Kb, Vtg, ctxb);

    // 5. convert FFN weights into now-dead Q/K slots
    cvt_bf16_2<<<dim3(8192), 256, 0, stream>>>(W1, W2, W1b, W2b);

    // 6. output projection -> Fs (fp32)
    gemm_k64<<<dim3(8, 64), 256, 0, stream>>>(ctxb, Wob, bo, Fs,
                                              NTOK, D_MODEL, D_MODEL);

    // 7. x1 = LN(x + attn_out)
    ln_res<<<dim3(NTOK), 256, 0, stream>>>(x, Fs, g1, be1, x1, x1b);

    // 8. h = relu(x1 @ W1^T + b1)
    gemm_bt<128, 128, 1><<<dim3(32, 32), 256, 0, stream>>>(
        x1b, W1b, b1, hb, nullptr, NTOK, DFF, D_MODEL);

    // 9. ff = h @ W2^T + b2 -> Fs (fp32)
    gemm_k64<<<dim3(8, 64), 256, 0, stream>>>(hb, W2b, b2, Fs,
                                              NTOK, D_MODEL, DFF);

    // 10. out = LN(x1 + ff)
    ln_res<<<dim3(NTOK), 256, 0, stream>>>(x1, Fs, g2, be2, (float*)d_out, nullptr);
}